// Round 2
// baseline (109.961 us; speedup 1.0000x reference)
//
#include <hip/hip_runtime.h>
#include <stdint.h>

#define N      8192
#define KDIM   256
#define BM     128
#define TILES  (N / BM)                    // 64
#define NPAIRS (TILES * (TILES + 1) / 2)   // 2080
#define MARGIN 0.5f

typedef __bf16 bf16x8 __attribute__((ext_vector_type(8)));
typedef float  f32x4  __attribute__((ext_vector_type(4)));

// fp32 -> bf16 round-to-nearest-even (data has no NaN/Inf)
__device__ __forceinline__ unsigned short f2bf(float f) {
    unsigned u = __float_as_uint(f);
    unsigned r = u + 0x7fffu + ((u >> 16) & 1u);
    return (unsigned short)(r >> 16);
}
__device__ __forceinline__ float bf2f(unsigned short s) {
    return __uint_as_float(((unsigned)s) << 16);
}

// async global->LDS, 16 B/lane; LDS dest = wave-uniform base + lane*16
__device__ __forceinline__ void async_copy16(const void* g, void* l) {
    __builtin_amdgcn_global_load_lds(
        (__attribute__((address_space(1))) void*)(g),
        (__attribute__((address_space(3))) void*)(l),
        16, 0, 0);
}

// ---------------------------------------------------------------------------
// Prepass: fp32 -> bf16 (RNE) into ws + per-row sum of bf16(x)^2 (fp32).
// One wave per row: 64 lanes x float4.
// ---------------------------------------------------------------------------
__global__ __launch_bounds__(256) void prep_kernel(
        const float* __restrict__ X, unsigned short* __restrict__ Xb,
        float* __restrict__ sq) {
    int row  = blockIdx.x * 4 + (threadIdx.x >> 6);
    int lane = threadIdx.x & 63;

    float4 v = *((const float4*)(X + (size_t)row * KDIM) + lane);
    ushort4 o;
    o.x = f2bf(v.x); o.y = f2bf(v.y); o.z = f2bf(v.z); o.w = f2bf(v.w);
    float a = bf2f(o.x), b = bf2f(o.y), c = bf2f(o.z), d = bf2f(o.w);
    float ss = a * a + b * b + c * c + d * d;
    *((ushort4*)(Xb + (size_t)row * KDIM) + lane) = o;

    #pragma unroll
    for (int off = 32; off > 0; off >>= 1) ss += __shfl_down(ss, off, 64);
    if (lane == 0) sq[row] = ss;
}

// ---------------------------------------------------------------------------
// Main: triangular grid of 128x128 Gram tiles. Single barrier: A-tile staged
// for full K=256 into LDS (XOR-swizzled); B fragments stream from global/L2.
// 8 barrier-free k-steps of mfma_f32_16x16x32_bf16; fused loss epilogue.
// ---------------------------------------------------------------------------
__global__ __launch_bounds__(256) void loss_kernel(
        const unsigned short* __restrict__ Xb, const float* __restrict__ sq,
        const int* __restrict__ tgt, float* __restrict__ partials) {
    // ---- triangular decode: p -> (bi, bj), bi <= bj ----
    const int p = blockIdx.x;
    float tf = 2.0f * TILES + 1.0f;
    int bi = (int)((tf - sqrtf(tf * tf - 8.0f * (float)p)) * 0.5f);
    if (bi < 0) bi = 0;
    while (bi > 0 && (bi * TILES - bi * (bi - 1) / 2) > p) --bi;
    while (((bi + 1) * TILES - (bi + 1) * bi / 2) <= p) ++bi;
    const int bj = bi + (p - (bi * TILES - bi * (bi - 1) / 2));

    __shared__ __align__(16) unsigned short As[BM * KDIM];   // 64 KB
    __shared__ float sqa_s[BM], sqb_s[BM];
    __shared__ int   ta_s[BM],  tb_s[BM];
    __shared__ float wsum[4];

    const int tid  = threadIdx.x;
    const int wave = tid >> 6;
    const int lane = tid & 63;

    // epilogue metadata (visible after the single barrier)
    if (tid < 128) {
        sqa_s[tid] = sq[bi * BM + tid];
        ta_s[tid]  = tgt[bi * BM + tid];
    } else {
        int r = tid - 128;
        sqb_s[r] = sq[bj * BM + r];
        tb_s[r]  = tgt[bj * BM + r];
    }

    const size_t rowA0 = (size_t)bi * BM;
    const size_t rowB0 = (size_t)bj * BM;

    // ---- stage A tile (128 rows x 256 k, bf16) into LDS, XOR swizzle ----
    // row r stored as 32 granules of 16 B; LDS slot s holds global granule
    // s ^ (r & 7)  -> fragment ds_read_b128 is 2-way-conflict-only (free).
    {
        const int lr32 = lane >> 5;           // row within wave's 2-row slab
        const int slot = lane & 31;           // granule slot in row
        const int rw   = wave * 2 + lr32;     // 0..7
        const int g0   = slot ^ rw;           // i-invariant ((r&7)==rw)
        const unsigned short* gA = Xb + (rowA0 + rw) * KDIM + g0 * 8;
        char* ldst = (char*)As + wave * 2 * 512;   // wave-uniform
        #pragma unroll
        for (int i = 0; i < 16; ++i)
            async_copy16(gA + (size_t)i * 8 * KDIM, ldst + i * 4096);
    }
    __syncthreads();   // compiler emits vmcnt(0) drain before s_barrier

    const int frow  = lane & 15;
    const int fquad = lane >> 4;

    const int wm = (wave >> 1) * 64;
    const int wn = (wave & 1) * 64;

    f32x4 acc[4][4];
    #pragma unroll
    for (int im = 0; im < 4; ++im)
        #pragma unroll
        for (int in = 0; in < 4; ++in)
            acc[im][in] = (f32x4){0.f, 0.f, 0.f, 0.f};

    // B fragment pointers: row (rowB0 + n), k-offset fquad*8
    const unsigned short* bptr[4];
    #pragma unroll
    for (int in = 0; in < 4; ++in)
        bptr[in] = Xb + (rowB0 + wn + in * 16 + frow) * KDIM + fquad * 8;

    // A fragment LDS byte base per im (row m = wm + im*16 + frow)
    const char* abase = (const char*)As + (wm + frow) * 512;
    const int   fr7   = frow & 7;

    #pragma unroll
    for (int ks = 0; ks < 8; ++ks) {
        const int slotA = ((ks * 4 + fquad) ^ fr7) << 4;   // byte offset
        bf16x8 af[4], bfr[4];
        #pragma unroll
        for (int im = 0; im < 4; ++im)
            af[im] = *(const bf16x8*)(abase + im * 16 * 512 + slotA);
        #pragma unroll
        for (int in = 0; in < 4; ++in)
            bfr[in] = *(const bf16x8*)(bptr[in] + ks * 32);
        #pragma unroll
        for (int im = 0; im < 4; ++im)
            #pragma unroll
            for (int in = 0; in < 4; ++in)
                acc[im][in] = __builtin_amdgcn_mfma_f32_16x16x32_bf16(
                    af[im], bfr[in], acc[im][in], 0, 0, 0);
    }

    // ---- epilogue: C/D map col=lane&15, row=(lane>>4)*4+reg ----
    float lsum = 0.0f;
    if (bi != bj) {
        #pragma unroll
        for (int im = 0; im < 4; ++im) {
            #pragma unroll
            for (int in = 0; in < 4; ++in) {
                #pragma unroll
                for (int r = 0; r < 4; ++r) {
                    int rl = wm + im * 16 + fquad * 4 + r;
                    int cl = wn + in * 16 + frow;
                    float d = fmaf(-2.0f, acc[im][in][r],
                                   sqa_s[rl] + sqb_s[cl]);
                    lsum += (ta_s[rl] == tb_s[cl]) ? d
                                                   : fmaxf(MARGIN - d, 0.0f);
                }
            }
        }
        lsum *= 2.0f;   // (i,j) and (j,i) pair weight
    } else {
        #pragma unroll
        for (int im = 0; im < 4; ++im) {
            #pragma unroll
            for (int in = 0; in < 4; ++in) {
                #pragma unroll
                for (int r = 0; r < 4; ++r) {
                    int rl = wm + im * 16 + fquad * 4 + r;
                    int cl = wn + in * 16 + frow;
                    float d = fmaf(-2.0f, acc[im][in][r],
                                   sqa_s[rl] + sqb_s[cl]);
                    float c = (ta_s[rl] == tb_s[cl]) ? d
                                                     : fmaxf(MARGIN - d, 0.0f);
                    float w = (rl < cl) ? 2.0f : ((rl == cl) ? 1.0f : 0.0f);
                    lsum += w * c;
                }
            }
        }
    }

    #pragma unroll
    for (int off = 32; off > 0; off >>= 1) lsum += __shfl_down(lsum, off, 64);
    if (lane == 0) wsum[wave] = lsum;
    __syncthreads();
    if (tid == 0) partials[p] = wsum[0] + wsum[1] + wsum[2] + wsum[3];
}

// ---------------------------------------------------------------------------
// Final deterministic reduce of NPAIRS partials -> scaled scalar.
// ---------------------------------------------------------------------------
__global__ __launch_bounds__(256) void reduce_kernel(
        const float* __restrict__ partials, float* __restrict__ out,
        int n, float scale) {
    float s = 0.0f;
    for (int i = threadIdx.x; i < n; i += 256) s += partials[i];
    __shared__ float w[4];
    #pragma unroll
    for (int off = 32; off > 0; off >>= 1) s += __shfl_down(s, off, 64);
    int wave = threadIdx.x >> 6, lane = threadIdx.x & 63;
    if (lane == 0) w[wave] = s;
    __syncthreads();
    if (threadIdx.x == 0) out[0] = (w[0] + w[1] + w[2] + w[3]) * scale;
}

extern "C" void kernel_launch(void* const* d_in, const int* in_sizes, int n_in,
                              void* d_out, int out_size, void* d_ws, size_t ws_size,
                              hipStream_t stream) {
    (void)in_sizes; (void)n_in; (void)out_size; (void)ws_size;
    const float* X   = (const float*)d_in[0];
    const int*   tgt = (const int*)d_in[1];

    unsigned short* Xb = (unsigned short*)d_ws;                     // 4 MB
    float* sq       = (float*)((char*)d_ws + (size_t)N * KDIM * 2);
    float* partials = sq + N;                                       // NPAIRS

    prep_kernel<<<N / 4, 256, 0, stream>>>(X, Xb, sq);
    loss_kernel<<<NPAIRS, 256, 0, stream>>>(Xb, sq, tgt, partials);

    const float scale = (float)(1.0 / ((double)N * ((double)N - 1.0) * 2.0));
    reduce_kernel<<<1, 256, 0, stream>>>(partials, (float*)d_out, NPAIRS, scale);
}

// Round 3
// 87.457 us; speedup vs baseline: 1.2573x; 1.2573x over previous
//
#include <hip/hip_runtime.h>
#include <stdint.h>

#define N      8192
#define KDIM   256
#define BM     128
#define TILES  (N / BM)                    // 64
#define NPAIRS (TILES * (TILES + 1) / 2)   // 2080
#define MARGIN 0.5f

typedef float f32x4 __attribute__((ext_vector_type(4)));

// async global->LDS, 16 B/lane; LDS dest = wave-uniform base + lane*16
__device__ __forceinline__ void async_copy16(const void* g, void* l) {
    __builtin_amdgcn_global_load_lds(
        (__attribute__((address_space(1))) void*)(g),
        (__attribute__((address_space(3))) void*)(l),
        16, 0, 0);
}

#if !__has_builtin(__builtin_amdgcn_cvt_pk_fp8_f32)
// manual fp32 -> e4m3fn RNE fallback (|x| small; no sat/NaN concerns)
__device__ __forceinline__ uint32_t f2e4m3(float f) {
    uint32_t u = __float_as_uint(f);
    uint32_t s = (u >> 24) & 0x80u;
    uint32_t au = u & 0x7fffffffu;
    if (au == 0) return s;
    int32_t  exp = (int32_t)(au >> 23) - 127;
    uint32_t man = (au & 0x7fffffu) | 0x800000u;   // 1.m in 2^23 units
    uint32_t code;
    if (exp >= -6) {                                // normal e4m3
        code = (uint32_t)((exp + 7) << 3) | ((man >> 20) & 7u);
        uint32_t rem = man & 0xFFFFFu;
        if (rem > 0x80000u || (rem == 0x80000u && (code & 1u))) code++;
    } else {                                        // subnormal: ulp 2^-9
        int shift = 14 - exp;                       // man >> shift = a*512
        if (shift > 24) return s;
        code = man >> shift;
        uint32_t rem = man & ((1u << shift) - 1u);
        uint32_t h = 1u << (shift - 1);
        if (rem > h || (rem == h && (code & 1u))) code++;
    }
    return s | code;
}
__device__ __forceinline__ uint32_t pack_fp8x4(float4 v) {
    return f2e4m3(v.x) | (f2e4m3(v.y) << 8) | (f2e4m3(v.z) << 16) |
           (f2e4m3(v.w) << 24);
}
#else
__device__ __forceinline__ uint32_t pack_fp8x4(float4 v) {
    int pk = __builtin_amdgcn_cvt_pk_fp8_f32(v.x, v.y, 0, false);
    pk = __builtin_amdgcn_cvt_pk_fp8_f32(v.z, v.w, pk, true);
    return (uint32_t)pk;
}
#endif

// ---------------------------------------------------------------------------
// Prepass: fp32 -> fp8 e4m3 into ws (rows stored 16B-granule-XOR-swizzled so
// the loss kernel's staging is contiguous and its ds_read_b64 conflict-free),
// plus EXACT fp32 row norms. One wave per row.
// ---------------------------------------------------------------------------
__global__ __launch_bounds__(256) void prep_kernel(
        const float* __restrict__ X, uint8_t* __restrict__ Xq,
        float* __restrict__ sq) {
    int row  = blockIdx.x * 4 + (threadIdx.x >> 6);
    int lane = threadIdx.x & 63;

    float4 v = *((const float4*)(X + (size_t)row * KDIM) + lane);
    float ss = v.x * v.x + v.y * v.y + v.z * v.z + v.w * v.w;
    uint32_t pk = pack_fp8x4(v);

    // lane covers k=4*lane..4*lane+3; 16B granule G=lane>>2 -> slot G^((row>>1)&7)
    int slot = (lane >> 2) ^ ((row >> 1) & 7);
    *(uint32_t*)(Xq + (size_t)row * KDIM + slot * 16 + (lane & 3) * 4) = pk;

    #pragma unroll
    for (int off = 32; off > 0; off >>= 1) ss += __shfl_down(ss, off, 64);
    if (lane == 0) sq[row] = ss;
}

// ---------------------------------------------------------------------------
// Main: triangular grid of 128x128 Gram tiles. Both tiles staged FULL-K into
// LDS (fp8: 2x32 KB) with one barrier; then 8 barrier-free k-steps of
// mfma_f32_16x16x32_fp8_fp8 fed purely from LDS. Fused loss epilogue.
// ---------------------------------------------------------------------------
__global__ __launch_bounds__(256, 2) void loss_kernel(
        const uint8_t* __restrict__ Xq, const float* __restrict__ sq,
        const int* __restrict__ tgt, float* __restrict__ partials) {
    // ---- triangular decode: p -> (bi, bj), bi <= bj ----
    const int p = blockIdx.x;
    float tf = 2.0f * TILES + 1.0f;
    int bi = (int)((tf - sqrtf(tf * tf - 8.0f * (float)p)) * 0.5f);
    if (bi < 0) bi = 0;
    while (bi > 0 && (bi * TILES - bi * (bi - 1) / 2) > p) --bi;
    while (((bi + 1) * TILES - (bi + 1) * bi / 2) <= p) ++bi;
    const int bj = bi + (p - (bi * TILES - bi * (bi - 1) / 2));

    __shared__ __align__(16) uint8_t As[BM * KDIM];   // 32 KB (swizzled rows)
    __shared__ __align__(16) uint8_t Bs[BM * KDIM];   // 32 KB
    __shared__ float sqa_s[BM], sqb_s[BM];
    __shared__ int   ta_s[BM],  tb_s[BM];
    __shared__ float wsum[4];

    const int tid  = threadIdx.x;
    const int wave = tid >> 6;
    const int lane = tid & 63;

    if (tid < 128) {
        sqa_s[tid] = sq[bi * BM + tid];
        ta_s[tid]  = tgt[bi * BM + tid];
    } else {
        int r = tid - 128;
        sqb_s[r] = sq[bj * BM + r];
        tb_s[r]  = tgt[bj * BM + r];
    }

    // ---- stage both tiles: contiguous 1 KB per instruction (pre-swizzled) ----
    {
        const uint8_t* gA = Xq + ((size_t)bi * BM + wave * 32) * KDIM;
        const uint8_t* gB = Xq + ((size_t)bj * BM + wave * 32) * KDIM;
        uint8_t* lA = As + wave * 32 * KDIM;
        uint8_t* lB = Bs + wave * 32 * KDIM;
        #pragma unroll
        for (int i = 0; i < 8; ++i) {
            async_copy16(gA + i * 1024 + lane * 16, lA + i * 1024);
            async_copy16(gB + i * 1024 + lane * 16, lB + i * 1024);
        }
    }
    __syncthreads();

    const int frow  = lane & 15;
    const int fquad = lane >> 4;
    const int wm = (wave >> 1) * 64;
    const int wn = (wave & 1) * 64;
    const int swz = (frow >> 1) & 7;        // row-swizzle key (im/in-invariant)
    const int fq2 = fquad >> 1;
    const int fqh = (fquad & 1) * 8;

    const uint8_t* abase = As + (wm + frow) * 256 + fqh;
    const uint8_t* bbase = Bs + (wn + frow) * 256 + fqh;

    f32x4 acc[4][4];
    #pragma unroll
    for (int im = 0; im < 4; ++im)
        #pragma unroll
        for (int in = 0; in < 4; ++in)
            acc[im][in] = (f32x4){0.f, 0.f, 0.f, 0.f};

    #pragma unroll
    for (int ks = 0; ks < 8; ++ks) {
        const int t = ((ks * 2 + fq2) ^ swz) * 16;   // swizzled 16B-slot byte off
        long long af[4], bfr[4];
        #pragma unroll
        for (int im = 0; im < 4; ++im)
            af[im] = *(const long long*)(abase + im * 16 * 256 + t);
        #pragma unroll
        for (int in = 0; in < 4; ++in)
            bfr[in] = *(const long long*)(bbase + in * 16 * 256 + t);
        #pragma unroll
        for (int im = 0; im < 4; ++im)
            #pragma unroll
            for (int in = 0; in < 4; ++in)
                acc[im][in] = __builtin_amdgcn_mfma_f32_16x16x32_fp8_fp8(
                    af[im], bfr[in], acc[im][in], 0, 0, 0);
    }

    // ---- epilogue: C/D map col=lane&15, row=(lane>>4)*4+reg ----
    float lsum = 0.0f;
    if (bi != bj) {
        #pragma unroll
        for (int im = 0; im < 4; ++im) {
            #pragma unroll
            for (int in = 0; in < 4; ++in) {
                #pragma unroll
                for (int r = 0; r < 4; ++r) {
                    int rl = wm + im * 16 + fquad * 4 + r;
                    int cl = wn + in * 16 + frow;
                    float d = fmaf(-2.0f, acc[im][in][r],
                                   sqa_s[rl] + sqb_s[cl]);
                    lsum += (ta_s[rl] == tb_s[cl]) ? d
                                                   : fmaxf(MARGIN - d, 0.0f);
                }
            }
        }
        lsum *= 2.0f;   // (i,j) and (j,i)
    } else {
        #pragma unroll
        for (int im = 0; im < 4; ++im) {
            #pragma unroll
            for (int in = 0; in < 4; ++in) {
                #pragma unroll
                for (int r = 0; r < 4; ++r) {
                    int rl = wm + im * 16 + fquad * 4 + r;
                    int cl = wn + in * 16 + frow;
                    float d = fmaf(-2.0f, acc[im][in][r],
                                   sqa_s[rl] + sqb_s[cl]);
                    float c = (ta_s[rl] == tb_s[cl]) ? d
                                                     : fmaxf(MARGIN - d, 0.0f);
                    float w = (rl < cl) ? 2.0f : ((rl == cl) ? 1.0f : 0.0f);
                    lsum += w * c;
                }
            }
        }
    }

    #pragma unroll
    for (int off = 32; off > 0; off >>= 1) lsum += __shfl_down(lsum, off, 64);
    if (lane == 0) wsum[wave] = lsum;
    __syncthreads();
    if (tid == 0) partials[p] = wsum[0] + wsum[1] + wsum[2] + wsum[3];
}

// ---------------------------------------------------------------------------
// Final deterministic reduce of NPAIRS partials -> scaled scalar.
// ---------------------------------------------------------------------------
__global__ __launch_bounds__(256) void reduce_kernel(
        const float* __restrict__ partials, float* __restrict__ out,
        int n, float scale) {
    float s = 0.0f;
    for (int i = threadIdx.x; i < n; i += 256) s += partials[i];
    __shared__ float w[4];
    #pragma unroll
    for (int off = 32; off > 0; off >>= 1) s += __shfl_down(s, off, 64);
    int wave = threadIdx.x >> 6, lane = threadIdx.x & 63;
    if (lane == 0) w[wave] = s;
    __syncthreads();
    if (threadIdx.x == 0) out[0] = (w[0] + w[1] + w[2] + w[3]) * scale;
}

extern "C" void kernel_launch(void* const* d_in, const int* in_sizes, int n_in,
                              void* d_out, int out_size, void* d_ws, size_t ws_size,
                              hipStream_t stream) {
    (void)in_sizes; (void)n_in; (void)out_size; (void)ws_size;
    const float* X   = (const float*)d_in[0];
    const int*   tgt = (const int*)d_in[1];

    uint8_t* Xq     = (uint8_t*)d_ws;                              // 2 MB fp8
    float* sq       = (float*)((char*)d_ws + (size_t)N * KDIM);
    float* partials = sq + N;                                      // NPAIRS

    prep_kernel<<<N / 4, 256, 0, stream>>>(X, Xq, sq);
    loss_kernel<<<NPAIRS, 256, 0, stream>>>(Xq, sq, tgt, partials);

    const float scale = (float)(1.0 / ((double)N * ((double)N - 1.0) * 2.0));
    reduce_kernel<<<1, 256, 0, stream>>>(partials, (float*)d_out, NPAIRS, scale);
}

// Round 4
// 80.737 us; speedup vs baseline: 1.3620x; 1.0832x over previous
//
#include <hip/hip_runtime.h>
#include <stdint.h>

#define N      8192
#define KDIM   256
#define BM     128
#define TILES  (N / BM)                    // 64
#define NPAIRS (TILES * (TILES + 1) / 2)   // 2080
#define MARGIN 0.5f

typedef float     f32x4 __attribute__((ext_vector_type(4)));
typedef long long i64x2 __attribute__((ext_vector_type(2)));

// async global->LDS, 16 B/lane; LDS dest = wave-uniform base + lane*16
__device__ __forceinline__ void async_copy16(const void* g, void* l) {
    __builtin_amdgcn_global_load_lds(
        (__attribute__((address_space(1))) void*)(g),
        (__attribute__((address_space(3))) void*)(l),
        16, 0, 0);
}

#if !__has_builtin(__builtin_amdgcn_cvt_pk_fp8_f32)
// manual fp32 -> e4m3fn RNE fallback
__device__ __forceinline__ uint32_t f2e4m3(float f) {
    uint32_t u = __float_as_uint(f);
    uint32_t s = (u >> 24) & 0x80u;
    uint32_t au = u & 0x7fffffffu;
    if (au == 0) return s;
    int32_t  exp = (int32_t)(au >> 23) - 127;
    uint32_t man = (au & 0x7fffffu) | 0x800000u;
    uint32_t code;
    if (exp >= -6) {
        code = (uint32_t)((exp + 7) << 3) | ((man >> 20) & 7u);
        uint32_t rem = man & 0xFFFFFu;
        if (rem > 0x80000u || (rem == 0x80000u && (code & 1u))) code++;
    } else {
        int shift = 14 - exp;
        if (shift > 24) return s;
        code = man >> shift;
        uint32_t rem = man & ((1u << shift) - 1u);
        uint32_t h = 1u << (shift - 1);
        if (rem > h || (rem == h && (code & 1u))) code++;
    }
    return s | code;
}
__device__ __forceinline__ uint32_t pack_fp8x4(float4 v) {
    return f2e4m3(v.x) | (f2e4m3(v.y) << 8) | (f2e4m3(v.z) << 16) |
           (f2e4m3(v.w) << 24);
}
#else
__device__ __forceinline__ uint32_t pack_fp8x4(float4 v) {
    int pk = __builtin_amdgcn_cvt_pk_fp8_f32(v.x, v.y, 0, false);
    pk = __builtin_amdgcn_cvt_pk_fp8_f32(v.z, v.w, pk, true);
    return (uint32_t)pk;
}
#endif

// ---------------------------------------------------------------------------
// Prepass: fp32 -> fp8 e4m3, stored in the loss kernel's LDS-ready layout:
// row = [half0 128B][half1 128B]; each half = 8 16B slots; slot index
// (fquad*2 + ks2) ^ (row&7); slot = {chunk ks even (8B), chunk ks odd (8B)}.
// Exact fp32 row norms. One wave per row.
// ---------------------------------------------------------------------------
__global__ __launch_bounds__(256) void prep_kernel(
        const float* __restrict__ X, uint8_t* __restrict__ Xq,
        float* __restrict__ sq) {
    int row  = blockIdx.x * 4 + (threadIdx.x >> 6);
    int lane = threadIdx.x & 63;

    float4 v = *((const float4*)(X + (size_t)row * KDIM) + lane);
    float ss = v.x * v.x + v.y * v.y + v.z * v.z + v.w * v.w;
    uint32_t pk = pack_fp8x4(v);

    int kg = lane * 4;            // global k of first element
    int h  = kg >> 7;             // K-half
    int kh = kg & 127;
    int ks = kh >> 5;             // k-step within half (0..3)
    int fq = (kh >> 3) & 3;       // fquad owning this chunk
    int slot = (fq * 2 + (ks >> 1)) ^ (row & 7);
    size_t off = (size_t)row * 256 + h * 128 + slot * 16 + (ks & 1) * 8 + (kh & 4);
    *(uint32_t*)(Xq + off) = pk;

    #pragma unroll
    for (int o = 32; o > 0; o >>= 1) ss += __shfl_down(ss, o, 64);
    if (lane == 0) sq[row] = ss;
}

// ---------------------------------------------------------------------------
// Main: triangular grid of 128x128 Gram tiles, fp8 MFMA. BK=128 halves so
// LDS = 32KB+meta -> 4 blocks/CU (16 waves/CU). ds_read_b128 fragments
// (swizzled, bank-minimal). Fused contrastive-loss epilogue.
// ---------------------------------------------------------------------------
__global__ __launch_bounds__(256, 4) void loss_kernel(
        const uint8_t* __restrict__ Xq, const float* __restrict__ sq,
        const int* __restrict__ tgt, float* __restrict__ partials) {
    // ---- triangular decode: p -> (bi, bj), bi <= bj ----
    const int p = blockIdx.x;
    float tf = 2.0f * TILES + 1.0f;
    int bi = (int)((tf - sqrtf(tf * tf - 8.0f * (float)p)) * 0.5f);
    if (bi < 0) bi = 0;
    while (bi > 0 && (bi * TILES - bi * (bi - 1) / 2) > p) --bi;
    while (((bi + 1) * TILES - (bi + 1) * bi / 2) <= p) ++bi;
    const int bj = bi + (p - (bi * TILES - bi * (bi - 1) / 2));

    __shared__ __align__(16) uint8_t As[BM * 128];   // 16 KB (one K-half)
    __shared__ __align__(16) uint8_t Bs[BM * 128];   // 16 KB
    __shared__ float sqa_s[BM], sqb_s[BM];
    __shared__ int   ta_s[BM],  tb_s[BM];
    __shared__ float wsum[4];

    const int tid  = threadIdx.x;
    const int wave = tid >> 6;
    const int lane = tid & 63;

    if (tid < 128) {
        sqa_s[tid] = sq[bi * BM + tid];
        ta_s[tid]  = tgt[bi * BM + tid];
    } else {
        int r = tid - 128;
        sqb_s[r] = sq[bj * BM + r];
        tb_s[r]  = tgt[bj * BM + r];
    }

    // staging lane decomposition: 8 rows x 8 slots(16B) per instruction
    const int lrow = lane >> 3;            // row within 8-row group
    const int lb   = (lane & 7) * 16;      // byte within 128B half-row
    const uint8_t* gA0 = Xq + ((size_t)bi * BM + wave * 32 + lrow) * 256 + lb;
    const uint8_t* gB0 = Xq + ((size_t)bj * BM + wave * 32 + lrow) * 256 + lb;
    uint8_t* lA = As + wave * 32 * 128;    // wave-uniform LDS bases
    uint8_t* lB = Bs + wave * 32 * 128;

    const int frow  = lane & 15;
    const int fquad = lane >> 4;
    const int wm = (wave >> 1) * 64;
    const int wn = (wave & 1) * 64;
    const int key = frow & 7;
    const uint8_t* aB = As + (wm + frow) * 128;
    const uint8_t* bB = Bs + (wn + frow) * 128;

    f32x4 acc[4][4];
    #pragma unroll
    for (int im = 0; im < 4; ++im)
        #pragma unroll
        for (int in = 0; in < 4; ++in)
            acc[im][in] = (f32x4){0.f, 0.f, 0.f, 0.f};

    #pragma unroll
    for (int h = 0; h < 2; ++h) {
        // stage K-half h (A: 16KB, B: 16KB across 4 waves)
        #pragma unroll
        for (int q = 0; q < 4; ++q) {
            async_copy16(gA0 + h * 128 + q * 8 * 256, lA + q * 1024);
            async_copy16(gB0 + h * 128 + q * 8 * 256, lB + q * 1024);
        }
        __syncthreads();

        #pragma unroll
        for (int ks2 = 0; ks2 < 2; ++ks2) {
            const int t = ((fquad * 2 + ks2) ^ key) * 16;
            i64x2 a2[4], b2[4];
            #pragma unroll
            for (int im = 0; im < 4; ++im)
                a2[im] = *(const i64x2*)(aB + im * 16 * 128 + t);
            #pragma unroll
            for (int in = 0; in < 4; ++in)
                b2[in] = *(const i64x2*)(bB + in * 16 * 128 + t);
            #pragma unroll
            for (int im = 0; im < 4; ++im)
                #pragma unroll
                for (int in = 0; in < 4; ++in)
                    acc[im][in] = __builtin_amdgcn_mfma_f32_16x16x32_fp8_fp8(
                        a2[im].x, b2[in].x, acc[im][in], 0, 0, 0);
            #pragma unroll
            for (int im = 0; im < 4; ++im)
                #pragma unroll
                for (int in = 0; in < 4; ++in)
                    acc[im][in] = __builtin_amdgcn_mfma_f32_16x16x32_fp8_fp8(
                        a2[im].y, b2[in].y, acc[im][in], 0, 0, 0);
        }
        if (h == 0) __syncthreads();   // LDS reuse guard before restaging
    }

    // ---- epilogue: C/D map col=lane&15, row=(lane>>4)*4+reg ----
    float lsum = 0.0f;
    if (bi != bj) {
        #pragma unroll
        for (int im = 0; im < 4; ++im) {
            #pragma unroll
            for (int in = 0; in < 4; ++in) {
                #pragma unroll
                for (int r = 0; r < 4; ++r) {
                    int rl = wm + im * 16 + fquad * 4 + r;
                    int cl = wn + in * 16 + frow;
                    float d = fmaf(-2.0f, acc[im][in][r],
                                   sqa_s[rl] + sqb_s[cl]);
                    lsum += (ta_s[rl] == tb_s[cl]) ? d
                                                   : fmaxf(MARGIN - d, 0.0f);
                }
            }
        }
        lsum *= 2.0f;   // (i,j) and (j,i)
    } else {
        #pragma unroll
        for (int im = 0; im < 4; ++im) {
            #pragma unroll
            for (int in = 0; in < 4; ++in) {
                #pragma unroll
                for (int r = 0; r < 4; ++r) {
                    int rl = wm + im * 16 + fquad * 4 + r;
                    int cl = wn + in * 16 + frow;
                    float d = fmaf(-2.0f, acc[im][in][r],
                                   sqa_s[rl] + sqb_s[cl]);
                    float c = (ta_s[rl] == tb_s[cl]) ? d
                                                     : fmaxf(MARGIN - d, 0.0f);
                    float w = (rl < cl) ? 2.0f : ((rl == cl) ? 1.0f : 0.0f);
                    lsum += w * c;
                }
            }
        }
    }

    #pragma unroll
    for (int o = 32; o > 0; o >>= 1) lsum += __shfl_down(lsum, o, 64);
    if (lane == 0) wsum[wave] = lsum;
    __syncthreads();
    if (tid == 0) partials[p] = wsum[0] + wsum[1] + wsum[2] + wsum[3];
}

// ---------------------------------------------------------------------------
// Final deterministic reduce of NPAIRS partials -> scaled scalar.
// ---------------------------------------------------------------------------
__global__ __launch_bounds__(256) void reduce_kernel(
        const float* __restrict__ partials, float* __restrict__ out,
        int n, float scale) {
    float s = 0.0f;
    for (int i = threadIdx.x; i < n; i += 256) s += partials[i];
    __shared__ float w[4];
    #pragma unroll
    for (int o = 32; o > 0; o >>= 1) s += __shfl_down(s, o, 64);
    int wave = threadIdx.x >> 6, lane = threadIdx.x & 63;
    if (lane == 0) w[wave] = s;
    __syncthreads();
    if (threadIdx.x == 0) out[0] = (w[0] + w[1] + w[2] + w[3]) * scale;
}

extern "C" void kernel_launch(void* const* d_in, const int* in_sizes, int n_in,
                              void* d_out, int out_size, void* d_ws, size_t ws_size,
                              hipStream_t stream) {
    (void)in_sizes; (void)n_in; (void)out_size; (void)ws_size;
    const float* X   = (const float*)d_in[0];
    const int*   tgt = (const int*)d_in[1];

    uint8_t* Xq     = (uint8_t*)d_ws;                              // 2 MB fp8
    float* sq       = (float*)((char*)d_ws + (size_t)N * KDIM);
    float* partials = sq + N;                                      // NPAIRS

    prep_kernel<<<N / 4, 256, 0, stream>>>(X, Xq, sq);
    loss_kernel<<<NPAIRS, 256, 0, stream>>>(Xq, sq, tgt, partials);

    const float scale = (float)(1.0 / ((double)N * ((double)N - 1.0) * 2.0));
    reduce_kernel<<<1, 256, 0, stream>>>(partials, (float*)d_out, NPAIRS, scale);
}